// Round 11
// baseline (826.969 us; speedup 1.0000x reference)
//
#include <hip/hip_runtime.h>
#include <stdint.h>

// BasicBlock: binarized ShuffleNet-style block via XNOR-popcount conv.
// conv = 128*nv - 2*popcount(bits_in ^ bits_w) over valid taps (exact integers).
// R11: tap-outer/channel-inner conv loop. R10's VGPR=40 showed the 36-reg
// window starved the scheduler (no weight prefetch -> serial ds_read waits,
// VALUBusy 54%). Tap-outer keeps ~12 live regs in the inner loop.

#define HH 56
#define WW 56
#define HW 3136
#define NBATCH 32
#define NPX (NBATCH * HW)   // 100352

// ws layout (bytes)
#define WS_W1B   0u          // 128*9 uint4 = 18432
#define WS_W2B   18432u      // 18432
#define WS_BN    36864u      // floats inv1[128] c1[128] inv2[128] c2[128]
#define WS_BITS2 40960u      // uint4 per pixel: 100352*16 = 1605632
#define WS_BITS1 1646592u    // 1605632
#define WS_RES1  3252224u    // int8 [8 groups][NPX][8B] = 6422528 (end 9.7MB)

#define PC(a,b) (__popc((a).x ^ (b).x) + __popc((a).y ^ (b).y) + \
                 __popc((a).z ^ (b).z) + __popc((a).w ^ (b).w))

// Kernel A: blocks 0..1959: per-pixel packing + pass-through planes.
// Blocks 1960..1969: weight binarization + bn constant prep.
__global__ __launch_bounds__(256) void binpack_kernel(
    const float* __restrict__ x, const float* __restrict__ move0,
    const float* __restrict__ move1,
    const float* __restrict__ w1, const float* __restrict__ w2,
    const float* __restrict__ g1, const float* __restrict__ b1,
    const float* __restrict__ m1, const float* __restrict__ v1,
    const float* __restrict__ g2, const float* __restrict__ b2,
    const float* __restrict__ m2, const float* __restrict__ v2,
    uint4* __restrict__ bits1, uint4* __restrict__ bits2,
    uint4* __restrict__ w1b, uint4* __restrict__ w2b, float* __restrict__ bnc,
    float* __restrict__ out)
{
    if (blockIdx.x >= 1960) {           // ---- prep section ----
        int t = (blockIdx.x - 1960) * 256 + threadIdx.x;
        if (t < 2304) {
            const float* w = (t < 1152) ? w1 : w2;
            uint4* dst = (t < 1152) ? w1b : w2b;
            int tt = (t < 1152) ? t : t - 1152;
            int o = tt / 9, tap = tt % 9;
            const float* wp = w + (size_t)o * 1152 + tap;
            uint32_t b[4];
            #pragma unroll
            for (int wd = 0; wd < 4; ++wd) {
                uint32_t acc = 0;
                #pragma unroll
                for (int bi = 0; bi < 32; ++bi) {
                    float wv = wp[(size_t)(wd * 32 + bi) * 9];
                    acc |= (wv >= 0.0f ? 1u : 0u) << bi;
                }
                b[wd] = acc;
            }
            dst[o * 9 + tap] = make_uint4(b[0], b[1], b[2], b[3]);
        } else if (t < 2432) {
            int c = t - 2304;
            float i1 = __fdiv_rn(g1[c], __fsqrt_rn(__fadd_rn(v1[c], 1e-5f)));
            bnc[c]       = i1;
            bnc[128 + c] = __fsub_rn(b1[c], __fmul_rn(m1[c], i1));
            float i2 = __fdiv_rn(g2[c], __fsqrt_rn(__fadd_rn(v2[c], 1e-5f)));
            bnc[256 + c] = i2;
            bnc[384 + c] = __fsub_rn(b2[c], __fmul_rn(m2[c], i2));
        }
        return;
    }

    const int g = blockIdx.x / 392;
    const int px = (blockIdx.x % 392) * 256 + threadIdx.x;   // < NPX exactly
    const int n = px / HW, poff = px % HW;
    const float* xn = x + (size_t)n * 256 * HW + poff;

    if (g < 2) {
        const int cb = g * 64;
        uint32_t w0 = 0, w1v = 0;
        #pragma unroll
        for (int c = 0; c < 32; ++c)
            w0 |= (xn[(size_t)(cb + c) * HW] >= 0.0f ? 1u : 0u) << c;
        #pragma unroll
        for (int c = 0; c < 32; ++c)
            w1v |= (xn[(size_t)(cb + 32 + c) * HW] >= 0.0f ? 1u : 0u) << c;
        ((uint2*)&bits1[px])[g] = make_uint2(w0, w1v);
    } else if (g == 2) {
        uint32_t w0 = 0, w1v = 0, w2v = 0, w3 = 0;
        #pragma unroll
        for (int k = 0; k < 64; ++k) {
            float s = __fadd_rn(xn[(size_t)(128 + k) * HW], move0[k]);
            uint32_t m = (s >= 0.0f ? 1u : 0u) << (2 * (k & 15) + 1);
            if ((k >> 4) == 0) w0 |= m; else if ((k >> 4) == 1) w1v |= m;
            else if ((k >> 4) == 2) w2v |= m; else w3 |= m;
        }
        bits2[px] = make_uint4(w0, w1v, w2v, w3);
    } else {
        const int mb = (g - 3) * 32;
        for (int mm = 0; mm < 32; ++mm) {
            int m = mb + mm;
            float v = __fadd_rn(__fadd_rn(xn[(size_t)(192 + m) * HW],
                                          move0[64 + m]), move1[2 * m + 1]);
            out[(size_t)(n * 256 + 4 * m + 3) * HW + poff] = v;
        }
    }
}

// Conv kernels: 448 threads, strip of 8 rows (448 px) within one image.
// Tap-outer accumulation: for each tap, one window uint4 + per-channel
// weight broadcast from LDS. acc[8] int registers.

// Kernel B: conv1, js = b & 15 (j = 8js + jj, jj<8).
__global__ __launch_bounds__(448, 7) void conv1_kernel(
    const float* __restrict__ x, const uint4* __restrict__ w1b,
    const float* __restrict__ bnc, const float* __restrict__ move1,
    const uint4* __restrict__ bits1, uint4* __restrict__ bits2,
    uint2* __restrict__ res1, float* __restrict__ out)
{
    const int b = blockIdx.x;
    const int js = b & 15;
    const int s = b >> 4;
    const int n = s / 7, si = s % 7;
    const int tid = threadIdx.x;

    __shared__ uint4 sb[562];
    __shared__ uint4 wl[72];

    const int poff = 448 * si + tid;
    const float* xn = x + (size_t)n * 256 * HW;
    const size_t pxi = (size_t)n * HW + poff;

    // batched preloads: 8 residual streams + old idle bits
    float rres[8];
    #pragma unroll
    for (int jj = 0; jj < 8; ++jj)
        rres[jj] = xn[(size_t)(js * 8 + jj) * HW + poff];
    uint32_t old16 = 0;
    if (js < 8) old16 = ((const uint16_t*)(bits2 + pxi))[js];

    const uint4* bsrc = bits1 + (size_t)n * HW;
    const int base = 448 * si - 57;
    for (int i = tid; i < 562; i += 448) {
        int g = base + i;
        g = (g < 0) ? 0 : ((g > HW - 1) ? HW - 1 : g);
        sb[i] = bsrc[g];
    }
    if (tid < 72) wl[tid] = w1b[js * 72 + tid];
    __syncthreads();

    const int row = poff / WW, col = poff % WW;
    const int rok0 = (row >= 1), rok2 = (row <= HH - 2);
    const int cok0 = (col >= 1), cok2 = (col <= WW - 2);
    const uint32_t rs0 = rok0 ? ~0u : 0u, rs2 = rok2 ? ~0u : 0u;
    const uint32_t csL = cok0 ? ~0u : 0u, csR = cok2 ? ~0u : 0u;
    const int nvbase = ((1 + rok0 + rok2) * (1 + cok0 + cok2)) << 7;

    uint32_t msk[9];
    msk[0] = rs0 & csL; msk[1] = rs0;  msk[2] = rs0 & csR;
    msk[3] = csL;       msk[4] = ~0u;  msk[5] = csR;
    msk[6] = rs2 & csL; msk[7] = rs2;  msk[8] = rs2 & csR;
    const int offs[9] = {0, 1, 2, 56, 57, 58, 112, 113, 114};

    int acc[8] = {0, 0, 0, 0, 0, 0, 0, 0};
    #pragma unroll
    for (int t = 0; t < 9; ++t) {
        const uint4 iw = sb[tid + offs[t]];
        const int m = (int)msk[t];
        #pragma unroll
        for (int ch = 0; ch < 8; ++ch) {
            const uint4 wt = wl[ch * 9 + t];
            acc[ch] += PC(wt, iw) & m;
        }
    }

    uint32_t bw = old16;
    uint32_t q0 = 0, q1 = 0;        // 8 int8 res1 bytes

    #pragma unroll
    for (int jj = 0; jj < 8; ++jj) {
        const int j = js * 8 + jj;
        float convf = (float)(nvbase - (acc[jj] << 1));
        float bno = __fadd_rn(__fmul_rn(convf, bnc[j]), bnc[128 + j]);
        float v2 = __fadd_rn(bno, rres[jj]);
        float vc = fminf(fmaxf(v2, -1.0f), 1.0f);
        if (js < 8) {
            bw |= (v2 >= 0.0f ? 1u : 0u) << (2 * jj);
            uint32_t q = (uint32_t)(uint8_t)(int8_t)__float2int_rn(
                __fmul_rn(vc, 127.0f));
            uint32_t sh = 8 * (jj & 3);
            if (jj < 4) q0 |= q << sh; else q1 |= q << sh;
        } else {
            int m = j - 64;
            out[(size_t)(n * 256 + 4 * m + 1) * HW + poff] =
                __fadd_rn(vc, move1[2 * m]);
        }
    }
    if (js < 8) {
        res1[(size_t)js * NPX + pxi] = make_uint2(q0, q1);
        ((uint16_t*)(bits2 + pxi))[js] = (uint16_t)bw;
    }
}

// Kernel C: conv2, js = b & 15 (j = 8js + jj, jj<8). out plane 2j.
__global__ __launch_bounds__(448, 7) void conv2_kernel(
    const float* __restrict__ x, const uint4* __restrict__ w2b,
    const float* __restrict__ bnc, const float* __restrict__ move0,
    const uint4* __restrict__ bits2, const uint2* __restrict__ res1,
    float* __restrict__ out)
{
    const int b = blockIdx.x;
    const int js = b & 15;
    const int s = b >> 4;
    const int n = s / 7, si = s % 7;
    const int tid = threadIdx.x;

    __shared__ uint4 sb[562];
    __shared__ uint4 wl[72];

    const int poff = 448 * si + tid;
    const float* xn = x + (size_t)n * 256 * HW;
    const size_t pxi = (size_t)n * HW + poff;

    // batched per-thread global loads (4 int8 even-j residuals + 4 idle floats)
    const uint32_t rq = ((const uint32_t*)(res1 + (size_t)(js >> 1) * NPX + pxi))[js & 1];
    float ro[4];
    #pragma unroll
    for (int k = 0; k < 4; ++k)
        ro[k] = xn[(size_t)(128 + js * 4 + k) * HW + poff];

    const uint4* bsrc = bits2 + (size_t)n * HW;
    const int base = 448 * si - 57;
    for (int i = tid; i < 562; i += 448) {
        int g = base + i;
        g = (g < 0) ? 0 : ((g > HW - 1) ? HW - 1 : g);
        sb[i] = bsrc[g];
    }
    if (tid < 72) wl[tid] = w2b[js * 72 + tid];
    __syncthreads();

    const int row = poff / WW, col = poff % WW;
    const int rok0 = (row >= 1), rok2 = (row <= HH - 2);
    const int cok0 = (col >= 1), cok2 = (col <= WW - 2);
    const uint32_t rs0 = rok0 ? ~0u : 0u, rs2 = rok2 ? ~0u : 0u;
    const uint32_t csL = cok0 ? ~0u : 0u, csR = cok2 ? ~0u : 0u;
    const int nvbase = ((1 + rok0 + rok2) * (1 + cok0 + cok2)) << 7;

    uint32_t msk[9];
    msk[0] = rs0 & csL; msk[1] = rs0;  msk[2] = rs0 & csR;
    msk[3] = csL;       msk[4] = ~0u;  msk[5] = csR;
    msk[6] = rs2 & csL; msk[7] = rs2;  msk[8] = rs2 & csR;
    const int offs[9] = {0, 1, 2, 56, 57, 58, 112, 113, 114};

    int acc[8] = {0, 0, 0, 0, 0, 0, 0, 0};
    #pragma unroll
    for (int t = 0; t < 9; ++t) {
        const uint4 iw = sb[tid + offs[t]];
        const int m = (int)msk[t];
        #pragma unroll
        for (int ch = 0; ch < 8; ++ch) {
            const uint4 wt = wl[ch * 9 + t];
            acc[ch] += PC(wt, iw) & m;
        }
    }

    #pragma unroll
    for (int jj = 0; jj < 8; ++jj) {
        const int j = js * 8 + jj;
        float convf = (float)(nvbase - (acc[jj] << 1));
        float bno = __fadd_rn(__fmul_rn(convf, bnc[256 + j]), bnc[384 + j]);
        float resv;
        if (jj & 1) {
            resv = __fadd_rn(ro[jj >> 1], move0[j >> 1]);
        } else {
            int8_t q = (int8_t)(uint8_t)(rq >> (8 * (jj >> 1)));
            resv = __fmul_rn(__int2float_rn((int)q), 1.0f / 127.0f);
        }
        float v2 = __fadd_rn(bno, resv);
        float vc = fminf(fmaxf(v2, -1.0f), 1.0f);
        out[(size_t)(n * 256 + 2 * j) * HW + poff] = vc;
    }
}

extern "C" void kernel_launch(void* const* d_in, const int* in_sizes, int n_in,
                              void* d_out, int out_size, void* d_ws, size_t ws_size,
                              hipStream_t stream)
{
    const float* x   = (const float*)d_in[0];
    const float* w1  = (const float*)d_in[1];
    const float* w2  = (const float*)d_in[2];
    const float* g1  = (const float*)d_in[3];
    const float* b1  = (const float*)d_in[4];
    const float* m1  = (const float*)d_in[5];
    const float* v1  = (const float*)d_in[6];
    const float* g2  = (const float*)d_in[7];
    const float* b2  = (const float*)d_in[8];
    const float* m2  = (const float*)d_in[9];
    const float* v2  = (const float*)d_in[10];
    const float* mv0 = (const float*)d_in[11];
    const float* mv1 = (const float*)d_in[12];

    uint8_t* ws = (uint8_t*)d_ws;
    uint4* w1b = (uint4*)(ws + WS_W1B);
    uint4* w2b = (uint4*)(ws + WS_W2B);
    float* bnc = (float*)(ws + WS_BN);
    uint4* bits2 = (uint4*)(ws + WS_BITS2);
    uint4* bits1 = (uint4*)(ws + WS_BITS1);
    uint2* res1 = (uint2*)(ws + WS_RES1);
    float* outp = (float*)d_out;

    hipLaunchKernelGGL(binpack_kernel, dim3(392 * 5 + 10), dim3(256), 0, stream,
                       x, mv0, mv1, w1, w2, g1, b1, m1, v1, g2, b2, m2, v2,
                       bits1, bits2, w1b, w2b, bnc, outp);
    hipLaunchKernelGGL(conv1_kernel, dim3(224 * 16), dim3(448), 0, stream,
                       x, w1b, bnc, mv1, bits1, bits2, res1, outp);
    hipLaunchKernelGGL(conv2_kernel, dim3(224 * 16), dim3(448), 0, stream,
                       x, w2b, bnc, mv0, bits2, res1, outp);
}

// Round 12
// 235.350 us; speedup vs baseline: 3.5138x; 3.5138x over previous
//
#include <hip/hip_runtime.h>
#include <stdint.h>

// BasicBlock: binarized ShuffleNet-style block via XNOR-popcount conv.
// conv = 128*nv - 2*popcount(bits_in ^ bits_w) over valid taps (exact integers).
// R12: R11's tap-outer loop WITHOUT the __launch_bounds__(,7) occupancy
// pledge. R11's 7-wave/EU demand capped VGPRs so hard the compiler spilled
// acc/msk/rres to scratch (FETCH 37->821MB, VALUBusy 5%). Single-variable fix.

#define HH 56
#define WW 56
#define HW 3136
#define NBATCH 32
#define NPX (NBATCH * HW)   // 100352

// ws layout (bytes)
#define WS_W1B   0u          // 128*9 uint4 = 18432
#define WS_W2B   18432u      // 18432
#define WS_BN    36864u      // floats inv1[128] c1[128] inv2[128] c2[128]
#define WS_BITS2 40960u      // uint4 per pixel: 100352*16 = 1605632
#define WS_BITS1 1646592u    // 1605632
#define WS_RES1  3252224u    // int8 [8 groups][NPX][8B] = 6422528 (end 9.7MB)

#define PC(a,b) (__popc((a).x ^ (b).x) + __popc((a).y ^ (b).y) + \
                 __popc((a).z ^ (b).z) + __popc((a).w ^ (b).w))

// Kernel A: blocks 0..1959: per-pixel packing + pass-through planes.
// Blocks 1960..1969: weight binarization + bn constant prep.
__global__ __launch_bounds__(256) void binpack_kernel(
    const float* __restrict__ x, const float* __restrict__ move0,
    const float* __restrict__ move1,
    const float* __restrict__ w1, const float* __restrict__ w2,
    const float* __restrict__ g1, const float* __restrict__ b1,
    const float* __restrict__ m1, const float* __restrict__ v1,
    const float* __restrict__ g2, const float* __restrict__ b2,
    const float* __restrict__ m2, const float* __restrict__ v2,
    uint4* __restrict__ bits1, uint4* __restrict__ bits2,
    uint4* __restrict__ w1b, uint4* __restrict__ w2b, float* __restrict__ bnc,
    float* __restrict__ out)
{
    if (blockIdx.x >= 1960) {           // ---- prep section ----
        int t = (blockIdx.x - 1960) * 256 + threadIdx.x;
        if (t < 2304) {
            const float* w = (t < 1152) ? w1 : w2;
            uint4* dst = (t < 1152) ? w1b : w2b;
            int tt = (t < 1152) ? t : t - 1152;
            int o = tt / 9, tap = tt % 9;
            const float* wp = w + (size_t)o * 1152 + tap;
            uint32_t b[4];
            #pragma unroll
            for (int wd = 0; wd < 4; ++wd) {
                uint32_t acc = 0;
                #pragma unroll
                for (int bi = 0; bi < 32; ++bi) {
                    float wv = wp[(size_t)(wd * 32 + bi) * 9];
                    acc |= (wv >= 0.0f ? 1u : 0u) << bi;
                }
                b[wd] = acc;
            }
            dst[o * 9 + tap] = make_uint4(b[0], b[1], b[2], b[3]);
        } else if (t < 2432) {
            int c = t - 2304;
            float i1 = __fdiv_rn(g1[c], __fsqrt_rn(__fadd_rn(v1[c], 1e-5f)));
            bnc[c]       = i1;
            bnc[128 + c] = __fsub_rn(b1[c], __fmul_rn(m1[c], i1));
            float i2 = __fdiv_rn(g2[c], __fsqrt_rn(__fadd_rn(v2[c], 1e-5f)));
            bnc[256 + c] = i2;
            bnc[384 + c] = __fsub_rn(b2[c], __fmul_rn(m2[c], i2));
        }
        return;
    }

    const int g = blockIdx.x / 392;
    const int px = (blockIdx.x % 392) * 256 + threadIdx.x;   // < NPX exactly
    const int n = px / HW, poff = px % HW;
    const float* xn = x + (size_t)n * 256 * HW + poff;

    if (g < 2) {
        const int cb = g * 64;
        uint32_t w0 = 0, w1v = 0;
        #pragma unroll
        for (int c = 0; c < 32; ++c)
            w0 |= (xn[(size_t)(cb + c) * HW] >= 0.0f ? 1u : 0u) << c;
        #pragma unroll
        for (int c = 0; c < 32; ++c)
            w1v |= (xn[(size_t)(cb + 32 + c) * HW] >= 0.0f ? 1u : 0u) << c;
        ((uint2*)&bits1[px])[g] = make_uint2(w0, w1v);
    } else if (g == 2) {
        uint32_t w0 = 0, w1v = 0, w2v = 0, w3 = 0;
        #pragma unroll
        for (int k = 0; k < 64; ++k) {
            float s = __fadd_rn(xn[(size_t)(128 + k) * HW], move0[k]);
            uint32_t m = (s >= 0.0f ? 1u : 0u) << (2 * (k & 15) + 1);
            if ((k >> 4) == 0) w0 |= m; else if ((k >> 4) == 1) w1v |= m;
            else if ((k >> 4) == 2) w2v |= m; else w3 |= m;
        }
        bits2[px] = make_uint4(w0, w1v, w2v, w3);
    } else {
        const int mb = (g - 3) * 32;
        for (int mm = 0; mm < 32; ++mm) {
            int m = mb + mm;
            float v = __fadd_rn(__fadd_rn(xn[(size_t)(192 + m) * HW],
                                          move0[64 + m]), move1[2 * m + 1]);
            out[(size_t)(n * 256 + 4 * m + 3) * HW + poff] = v;
        }
    }
}

// Conv kernels: 448 threads, strip of 8 rows (448 px) within one image.
// Tap-outer accumulation: for each tap, one window uint4 + per-channel
// weight broadcast from LDS. acc[8] int registers.

// Kernel B: conv1, js = b & 15 (j = 8js + jj, jj<8).
__global__ __launch_bounds__(448) void conv1_kernel(
    const float* __restrict__ x, const uint4* __restrict__ w1b,
    const float* __restrict__ bnc, const float* __restrict__ move1,
    const uint4* __restrict__ bits1, uint4* __restrict__ bits2,
    uint2* __restrict__ res1, float* __restrict__ out)
{
    const int b = blockIdx.x;
    const int js = b & 15;
    const int s = b >> 4;
    const int n = s / 7, si = s % 7;
    const int tid = threadIdx.x;

    __shared__ uint4 sb[562];
    __shared__ uint4 wl[72];

    const int poff = 448 * si + tid;
    const float* xn = x + (size_t)n * 256 * HW;
    const size_t pxi = (size_t)n * HW + poff;

    // batched preloads: 8 residual streams + old idle bits
    float rres[8];
    #pragma unroll
    for (int jj = 0; jj < 8; ++jj)
        rres[jj] = xn[(size_t)(js * 8 + jj) * HW + poff];
    uint32_t old16 = 0;
    if (js < 8) old16 = ((const uint16_t*)(bits2 + pxi))[js];

    const uint4* bsrc = bits1 + (size_t)n * HW;
    const int base = 448 * si - 57;
    for (int i = tid; i < 562; i += 448) {
        int g = base + i;
        g = (g < 0) ? 0 : ((g > HW - 1) ? HW - 1 : g);
        sb[i] = bsrc[g];
    }
    if (tid < 72) wl[tid] = w1b[js * 72 + tid];
    __syncthreads();

    const int row = poff / WW, col = poff % WW;
    const int rok0 = (row >= 1), rok2 = (row <= HH - 2);
    const int cok0 = (col >= 1), cok2 = (col <= WW - 2);
    const uint32_t rs0 = rok0 ? ~0u : 0u, rs2 = rok2 ? ~0u : 0u;
    const uint32_t csL = cok0 ? ~0u : 0u, csR = cok2 ? ~0u : 0u;
    const int nvbase = ((1 + rok0 + rok2) * (1 + cok0 + cok2)) << 7;

    uint32_t msk[9];
    msk[0] = rs0 & csL; msk[1] = rs0;  msk[2] = rs0 & csR;
    msk[3] = csL;       msk[4] = ~0u;  msk[5] = csR;
    msk[6] = rs2 & csL; msk[7] = rs2;  msk[8] = rs2 & csR;
    const int offs[9] = {0, 1, 2, 56, 57, 58, 112, 113, 114};

    int acc[8] = {0, 0, 0, 0, 0, 0, 0, 0};
    #pragma unroll
    for (int t = 0; t < 9; ++t) {
        const uint4 iw = sb[tid + offs[t]];
        const int m = (int)msk[t];
        #pragma unroll
        for (int ch = 0; ch < 8; ++ch) {
            const uint4 wt = wl[ch * 9 + t];
            acc[ch] += PC(wt, iw) & m;
        }
    }

    uint32_t bw = old16;
    uint32_t q0 = 0, q1 = 0;        // 8 int8 res1 bytes

    #pragma unroll
    for (int jj = 0; jj < 8; ++jj) {
        const int j = js * 8 + jj;
        float convf = (float)(nvbase - (acc[jj] << 1));
        float bno = __fadd_rn(__fmul_rn(convf, bnc[j]), bnc[128 + j]);
        float v2 = __fadd_rn(bno, rres[jj]);
        float vc = fminf(fmaxf(v2, -1.0f), 1.0f);
        if (js < 8) {
            bw |= (v2 >= 0.0f ? 1u : 0u) << (2 * jj);
            uint32_t q = (uint32_t)(uint8_t)(int8_t)__float2int_rn(
                __fmul_rn(vc, 127.0f));
            uint32_t sh = 8 * (jj & 3);
            if (jj < 4) q0 |= q << sh; else q1 |= q << sh;
        } else {
            int m = j - 64;
            out[(size_t)(n * 256 + 4 * m + 1) * HW + poff] =
                __fadd_rn(vc, move1[2 * m]);
        }
    }
    if (js < 8) {
        res1[(size_t)js * NPX + pxi] = make_uint2(q0, q1);
        ((uint16_t*)(bits2 + pxi))[js] = (uint16_t)bw;
    }
}

// Kernel C: conv2, js = b & 15 (j = 8js + jj, jj<8). out plane 2j.
__global__ __launch_bounds__(448) void conv2_kernel(
    const float* __restrict__ x, const uint4* __restrict__ w2b,
    const float* __restrict__ bnc, const float* __restrict__ move0,
    const uint4* __restrict__ bits2, const uint2* __restrict__ res1,
    float* __restrict__ out)
{
    const int b = blockIdx.x;
    const int js = b & 15;
    const int s = b >> 4;
    const int n = s / 7, si = s % 7;
    const int tid = threadIdx.x;

    __shared__ uint4 sb[562];
    __shared__ uint4 wl[72];

    const int poff = 448 * si + tid;
    const float* xn = x + (size_t)n * 256 * HW;
    const size_t pxi = (size_t)n * HW + poff;

    // batched per-thread global loads (4 int8 even-j residuals + 4 idle floats)
    const uint32_t rq = ((const uint32_t*)(res1 + (size_t)(js >> 1) * NPX + pxi))[js & 1];
    float ro[4];
    #pragma unroll
    for (int k = 0; k < 4; ++k)
        ro[k] = xn[(size_t)(128 + js * 4 + k) * HW + poff];

    const uint4* bsrc = bits2 + (size_t)n * HW;
    const int base = 448 * si - 57;
    for (int i = tid; i < 562; i += 448) {
        int g = base + i;
        g = (g < 0) ? 0 : ((g > HW - 1) ? HW - 1 : g);
        sb[i] = bsrc[g];
    }
    if (tid < 72) wl[tid] = w2b[js * 72 + tid];
    __syncthreads();

    const int row = poff / WW, col = poff % WW;
    const int rok0 = (row >= 1), rok2 = (row <= HH - 2);
    const int cok0 = (col >= 1), cok2 = (col <= WW - 2);
    const uint32_t rs0 = rok0 ? ~0u : 0u, rs2 = rok2 ? ~0u : 0u;
    const uint32_t csL = cok0 ? ~0u : 0u, csR = cok2 ? ~0u : 0u;
    const int nvbase = ((1 + rok0 + rok2) * (1 + cok0 + cok2)) << 7;

    uint32_t msk[9];
    msk[0] = rs0 & csL; msk[1] = rs0;  msk[2] = rs0 & csR;
    msk[3] = csL;       msk[4] = ~0u;  msk[5] = csR;
    msk[6] = rs2 & csL; msk[7] = rs2;  msk[8] = rs2 & csR;
    const int offs[9] = {0, 1, 2, 56, 57, 58, 112, 113, 114};

    int acc[8] = {0, 0, 0, 0, 0, 0, 0, 0};
    #pragma unroll
    for (int t = 0; t < 9; ++t) {
        const uint4 iw = sb[tid + offs[t]];
        const int m = (int)msk[t];
        #pragma unroll
        for (int ch = 0; ch < 8; ++ch) {
            const uint4 wt = wl[ch * 9 + t];
            acc[ch] += PC(wt, iw) & m;
        }
    }

    #pragma unroll
    for (int jj = 0; jj < 8; ++jj) {
        const int j = js * 8 + jj;
        float convf = (float)(nvbase - (acc[jj] << 1));
        float bno = __fadd_rn(__fmul_rn(convf, bnc[256 + j]), bnc[384 + j]);
        float resv;
        if (jj & 1) {
            resv = __fadd_rn(ro[jj >> 1], move0[j >> 1]);
        } else {
            int8_t q = (int8_t)(uint8_t)(rq >> (8 * (jj >> 1)));
            resv = __fmul_rn(__int2float_rn((int)q), 1.0f / 127.0f);
        }
        float v2 = __fadd_rn(bno, resv);
        float vc = fminf(fmaxf(v2, -1.0f), 1.0f);
        out[(size_t)(n * 256 + 2 * j) * HW + poff] = vc;
    }
}

extern "C" void kernel_launch(void* const* d_in, const int* in_sizes, int n_in,
                              void* d_out, int out_size, void* d_ws, size_t ws_size,
                              hipStream_t stream)
{
    const float* x   = (const float*)d_in[0];
    const float* w1  = (const float*)d_in[1];
    const float* w2  = (const float*)d_in[2];
    const float* g1  = (const float*)d_in[3];
    const float* b1  = (const float*)d_in[4];
    const float* m1  = (const float*)d_in[5];
    const float* v1  = (const float*)d_in[6];
    const float* g2  = (const float*)d_in[7];
    const float* b2  = (const float*)d_in[8];
    const float* m2  = (const float*)d_in[9];
    const float* v2  = (const float*)d_in[10];
    const float* mv0 = (const float*)d_in[11];
    const float* mv1 = (const float*)d_in[12];

    uint8_t* ws = (uint8_t*)d_ws;
    uint4* w1b = (uint4*)(ws + WS_W1B);
    uint4* w2b = (uint4*)(ws + WS_W2B);
    float* bnc = (float*)(ws + WS_BN);
    uint4* bits2 = (uint4*)(ws + WS_BITS2);
    uint4* bits1 = (uint4*)(ws + WS_BITS1);
    uint2* res1 = (uint2*)(ws + WS_RES1);
    float* outp = (float*)d_out;

    hipLaunchKernelGGL(binpack_kernel, dim3(392 * 5 + 10), dim3(256), 0, stream,
                       x, mv0, mv1, w1, w2, g1, b1, m1, v1, g2, b2, m2, v2,
                       bits1, bits2, w1b, w2b, bnc, outp);
    hipLaunchKernelGGL(conv1_kernel, dim3(224 * 16), dim3(448), 0, stream,
                       x, w1b, bnc, mv1, bits1, bits2, res1, outp);
    hipLaunchKernelGGL(conv2_kernel, dim3(224 * 16), dim3(448), 0, stream,
                       x, w2b, bnc, mv0, bits2, res1, outp);
}

// Round 13
// 115.946 us; speedup vs baseline: 7.1324x; 2.0298x over previous
//
#include <hip/hip_runtime.h>
#include <stdint.h>

// BasicBlock: binarized ShuffleNet-style block via XNOR-popcount conv.
// conv = 128*nv - 2*popcount(bits_in ^ bits_w) over valid taps (exact integers).
// R13: channel-outer (R10 structure, proven no-spill) + weights read via
// WAVE-UNIFORM global pointer -> compiler emits s_load into SGPRs (zero VGPR
// cost, scalar cache), v_xor takes SGPR operand. No wl LDS, no ds_read chain.

#define HH 56
#define WW 56
#define HW 3136
#define NBATCH 32
#define NPX (NBATCH * HW)   // 100352

// ws layout (bytes)
#define WS_W1B   0u          // 128*9 uint4 = 18432
#define WS_W2B   18432u      // 18432
#define WS_BN    36864u      // floats inv1[128] c1[128] inv2[128] c2[128]
#define WS_BITS2 40960u      // uint4 per pixel: 100352*16 = 1605632
#define WS_BITS1 1646592u    // 1605632
#define WS_RES1  3252224u    // int8 [8 groups][NPX][8B] = 6422528 (end 9.7MB)

#define PC(a,b) (__popc((a).x ^ (b).x) + __popc((a).y ^ (b).y) + \
                 __popc((a).z ^ (b).z) + __popc((a).w ^ (b).w))

// Kernel A: blocks 0..1959: per-pixel packing + pass-through planes.
// Blocks 1960..1969: weight binarization + bn constant prep.
__global__ __launch_bounds__(256) void binpack_kernel(
    const float* __restrict__ x, const float* __restrict__ move0,
    const float* __restrict__ move1,
    const float* __restrict__ w1, const float* __restrict__ w2,
    const float* __restrict__ g1, const float* __restrict__ b1,
    const float* __restrict__ m1, const float* __restrict__ v1,
    const float* __restrict__ g2, const float* __restrict__ b2,
    const float* __restrict__ m2, const float* __restrict__ v2,
    uint4* __restrict__ bits1, uint4* __restrict__ bits2,
    uint4* __restrict__ w1b, uint4* __restrict__ w2b, float* __restrict__ bnc,
    float* __restrict__ out)
{
    if (blockIdx.x >= 1960) {           // ---- prep section ----
        int t = (blockIdx.x - 1960) * 256 + threadIdx.x;
        if (t < 2304) {
            const float* w = (t < 1152) ? w1 : w2;
            uint4* dst = (t < 1152) ? w1b : w2b;
            int tt = (t < 1152) ? t : t - 1152;
            int o = tt / 9, tap = tt % 9;
            const float* wp = w + (size_t)o * 1152 + tap;
            uint32_t b[4];
            #pragma unroll
            for (int wd = 0; wd < 4; ++wd) {
                uint32_t acc = 0;
                #pragma unroll
                for (int bi = 0; bi < 32; ++bi) {
                    float wv = wp[(size_t)(wd * 32 + bi) * 9];
                    acc |= (wv >= 0.0f ? 1u : 0u) << bi;
                }
                b[wd] = acc;
            }
            dst[o * 9 + tap] = make_uint4(b[0], b[1], b[2], b[3]);
        } else if (t < 2432) {
            int c = t - 2304;
            float i1 = __fdiv_rn(g1[c], __fsqrt_rn(__fadd_rn(v1[c], 1e-5f)));
            bnc[c]       = i1;
            bnc[128 + c] = __fsub_rn(b1[c], __fmul_rn(m1[c], i1));
            float i2 = __fdiv_rn(g2[c], __fsqrt_rn(__fadd_rn(v2[c], 1e-5f)));
            bnc[256 + c] = i2;
            bnc[384 + c] = __fsub_rn(b2[c], __fmul_rn(m2[c], i2));
        }
        return;
    }

    const int g = blockIdx.x / 392;
    const int px = (blockIdx.x % 392) * 256 + threadIdx.x;   // < NPX exactly
    const int n = px / HW, poff = px % HW;
    const float* xn = x + (size_t)n * 256 * HW + poff;

    if (g < 2) {
        const int cb = g * 64;
        uint32_t w0 = 0, w1v = 0;
        #pragma unroll
        for (int c = 0; c < 32; ++c)
            w0 |= (xn[(size_t)(cb + c) * HW] >= 0.0f ? 1u : 0u) << c;
        #pragma unroll
        for (int c = 0; c < 32; ++c)
            w1v |= (xn[(size_t)(cb + 32 + c) * HW] >= 0.0f ? 1u : 0u) << c;
        ((uint2*)&bits1[px])[g] = make_uint2(w0, w1v);
    } else if (g == 2) {
        uint32_t w0 = 0, w1v = 0, w2v = 0, w3 = 0;
        #pragma unroll
        for (int k = 0; k < 64; ++k) {
            float s = __fadd_rn(xn[(size_t)(128 + k) * HW], move0[k]);
            uint32_t m = (s >= 0.0f ? 1u : 0u) << (2 * (k & 15) + 1);
            if ((k >> 4) == 0) w0 |= m; else if ((k >> 4) == 1) w1v |= m;
            else if ((k >> 4) == 2) w2v |= m; else w3 |= m;
        }
        bits2[px] = make_uint4(w0, w1v, w2v, w3);
    } else {
        const int mb = (g - 3) * 32;
        for (int mm = 0; mm < 32; ++mm) {
            int m = mb + mm;
            float v = __fadd_rn(__fadd_rn(xn[(size_t)(192 + m) * HW],
                                          move0[64 + m]), move1[2 * m + 1]);
            out[(size_t)(n * 256 + 4 * m + 3) * HW + poff] = v;
        }
    }
}

// Conv kernels: 448 threads, strip of 8 rows (448 px) within one image.
// Channel-outer loop; weights via wave-uniform global pointer (SGPR loads).

// Kernel B: conv1, js = b & 15 (j = 8js + jj, jj<8).
__global__ __launch_bounds__(448) void conv1_kernel(
    const float* __restrict__ x, const uint4* __restrict__ w1b,
    const float* __restrict__ bnc, const float* __restrict__ move1,
    const uint4* __restrict__ bits1, uint4* __restrict__ bits2,
    uint2* __restrict__ res1, float* __restrict__ out)
{
    const int b = blockIdx.x;
    const int js = b & 15;
    const int s = b >> 4;
    const int n = s / 7, si = s % 7;
    const int tid = threadIdx.x;

    __shared__ uint4 sb[562];

    const int poff = 448 * si + tid;
    const float* xn = x + (size_t)n * 256 * HW;
    const size_t pxi = (size_t)n * HW + poff;
    const uint4* __restrict__ wjs = w1b + js * 72;   // wave-uniform base

    // batched preloads: 8 residual streams + old idle bits
    float rres[8];
    #pragma unroll
    for (int jj = 0; jj < 8; ++jj)
        rres[jj] = xn[(size_t)(js * 8 + jj) * HW + poff];
    uint32_t old16 = 0;
    if (js < 8) old16 = ((const uint16_t*)(bits2 + pxi))[js];

    const uint4* bsrc = bits1 + (size_t)n * HW;
    const int base = 448 * si - 57;
    for (int i = tid; i < 562; i += 448) {
        int g = base + i;
        g = (g < 0) ? 0 : ((g > HW - 1) ? HW - 1 : g);
        sb[i] = bsrc[g];
    }
    __syncthreads();

    const int row = poff / WW, col = poff % WW;
    const int rok0 = (row >= 1), rok2 = (row <= HH - 2);
    const int cok0 = (col >= 1), cok2 = (col <= WW - 2);
    const uint32_t rs0 = rok0 ? ~0u : 0u, rs2 = rok2 ? ~0u : 0u;
    const uint32_t csL = cok0 ? ~0u : 0u, csR = cok2 ? ~0u : 0u;
    const int nvbase = ((1 + rok0 + rok2) * (1 + cok0 + cok2)) << 7;
    const uint4 i00 = sb[tid];       const uint4 i01 = sb[tid + 1];
    const uint4 i02 = sb[tid + 2];   const uint4 i10 = sb[tid + 56];
    const uint4 i11 = sb[tid + 57];  const uint4 i12 = sb[tid + 58];
    const uint4 i20 = sb[tid + 112]; const uint4 i21 = sb[tid + 113];
    const uint4 i22 = sb[tid + 114];

    uint32_t bw = old16;
    uint32_t q0 = 0, q1 = 0;        // 8 int8 res1 bytes

    #pragma unroll
    for (int jj = 0; jj < 8; ++jj) {
        const int j = js * 8 + jj;
        int acc = 0;
        acc += PC(wjs[jj * 9 + 0], i00) & (int)(rs0 & csL);
        acc += PC(wjs[jj * 9 + 1], i01) & (int)rs0;
        acc += PC(wjs[jj * 9 + 2], i02) & (int)(rs0 & csR);
        acc += PC(wjs[jj * 9 + 3], i10) & (int)csL;
        acc += PC(wjs[jj * 9 + 4], i11);
        acc += PC(wjs[jj * 9 + 5], i12) & (int)csR;
        acc += PC(wjs[jj * 9 + 6], i20) & (int)(rs2 & csL);
        acc += PC(wjs[jj * 9 + 7], i21) & (int)rs2;
        acc += PC(wjs[jj * 9 + 8], i22) & (int)(rs2 & csR);
        float convf = (float)(nvbase - (acc << 1));
        float bno = __fadd_rn(__fmul_rn(convf, bnc[j]), bnc[128 + j]);
        float v2 = __fadd_rn(bno, rres[jj]);
        float vc = fminf(fmaxf(v2, -1.0f), 1.0f);
        if (js < 8) {
            bw |= (v2 >= 0.0f ? 1u : 0u) << (2 * jj);
            uint32_t q = (uint32_t)(uint8_t)(int8_t)__float2int_rn(
                __fmul_rn(vc, 127.0f));
            uint32_t sh = 8 * (jj & 3);
            if (jj < 4) q0 |= q << sh; else q1 |= q << sh;
        } else {
            int m = j - 64;
            out[(size_t)(n * 256 + 4 * m + 1) * HW + poff] =
                __fadd_rn(vc, move1[2 * m]);
        }
    }
    if (js < 8) {
        res1[(size_t)js * NPX + pxi] = make_uint2(q0, q1);
        ((uint16_t*)(bits2 + pxi))[js] = (uint16_t)bw;
    }
}

// Kernel C: conv2, js = b & 15 (j = 8js + jj, jj<8). out plane 2j.
__global__ __launch_bounds__(448) void conv2_kernel(
    const float* __restrict__ x, const uint4* __restrict__ w2b,
    const float* __restrict__ bnc, const float* __restrict__ move0,
    const uint4* __restrict__ bits2, const uint2* __restrict__ res1,
    float* __restrict__ out)
{
    const int b = blockIdx.x;
    const int js = b & 15;
    const int s = b >> 4;
    const int n = s / 7, si = s % 7;
    const int tid = threadIdx.x;

    __shared__ uint4 sb[562];

    const int poff = 448 * si + tid;
    const float* xn = x + (size_t)n * 256 * HW;
    const size_t pxi = (size_t)n * HW + poff;
    const uint4* __restrict__ wjs = w2b + js * 72;   // wave-uniform base

    // batched per-thread global loads (4 int8 even-j residuals + 4 idle floats)
    const uint32_t rq = ((const uint32_t*)(res1 + (size_t)(js >> 1) * NPX + pxi))[js & 1];
    float ro[4];
    #pragma unroll
    for (int k = 0; k < 4; ++k)
        ro[k] = xn[(size_t)(128 + js * 4 + k) * HW + poff];

    const uint4* bsrc = bits2 + (size_t)n * HW;
    const int base = 448 * si - 57;
    for (int i = tid; i < 562; i += 448) {
        int g = base + i;
        g = (g < 0) ? 0 : ((g > HW - 1) ? HW - 1 : g);
        sb[i] = bsrc[g];
    }
    __syncthreads();

    const int row = poff / WW, col = poff % WW;
    const int rok0 = (row >= 1), rok2 = (row <= HH - 2);
    const int cok0 = (col >= 1), cok2 = (col <= WW - 2);
    const uint32_t rs0 = rok0 ? ~0u : 0u, rs2 = rok2 ? ~0u : 0u;
    const uint32_t csL = cok0 ? ~0u : 0u, csR = cok2 ? ~0u : 0u;
    const int nvbase = ((1 + rok0 + rok2) * (1 + cok0 + cok2)) << 7;
    const uint4 i00 = sb[tid];       const uint4 i01 = sb[tid + 1];
    const uint4 i02 = sb[tid + 2];   const uint4 i10 = sb[tid + 56];
    const uint4 i11 = sb[tid + 57];  const uint4 i12 = sb[tid + 58];
    const uint4 i20 = sb[tid + 112]; const uint4 i21 = sb[tid + 113];
    const uint4 i22 = sb[tid + 114];

    #pragma unroll
    for (int jj = 0; jj < 8; ++jj) {
        const int j = js * 8 + jj;
        int acc = 0;
        acc += PC(wjs[jj * 9 + 0], i00) & (int)(rs0 & csL);
        acc += PC(wjs[jj * 9 + 1], i01) & (int)rs0;
        acc += PC(wjs[jj * 9 + 2], i02) & (int)(rs0 & csR);
        acc += PC(wjs[jj * 9 + 3], i10) & (int)csL;
        acc += PC(wjs[jj * 9 + 4], i11);
        acc += PC(wjs[jj * 9 + 5], i12) & (int)csR;
        acc += PC(wjs[jj * 9 + 6], i20) & (int)(rs2 & csL);
        acc += PC(wjs[jj * 9 + 7], i21) & (int)rs2;
        acc += PC(wjs[jj * 9 + 8], i22) & (int)(rs2 & csR);
        float convf = (float)(nvbase - (acc << 1));
        float bno = __fadd_rn(__fmul_rn(convf, bnc[256 + j]), bnc[384 + j]);
        float resv;
        if (jj & 1) {
            resv = __fadd_rn(ro[jj >> 1], move0[j >> 1]);
        } else {
            int8_t q = (int8_t)(uint8_t)(rq >> (8 * (jj >> 1)));
            resv = __fmul_rn(__int2float_rn((int)q), 1.0f / 127.0f);
        }
        float v2 = __fadd_rn(bno, resv);
        float vc = fminf(fmaxf(v2, -1.0f), 1.0f);
        out[(size_t)(n * 256 + 2 * j) * HW + poff] = vc;
    }
}

extern "C" void kernel_launch(void* const* d_in, const int* in_sizes, int n_in,
                              void* d_out, int out_size, void* d_ws, size_t ws_size,
                              hipStream_t stream)
{
    const float* x   = (const float*)d_in[0];
    const float* w1  = (const float*)d_in[1];
    const float* w2  = (const float*)d_in[2];
    const float* g1  = (const float*)d_in[3];
    const float* b1  = (const float*)d_in[4];
    const float* m1  = (const float*)d_in[5];
    const float* v1  = (const float*)d_in[6];
    const float* g2  = (const float*)d_in[7];
    const float* b2  = (const float*)d_in[8];
    const float* m2  = (const float*)d_in[9];
    const float* v2  = (const float*)d_in[10];
    const float* mv0 = (const float*)d_in[11];
    const float* mv1 = (const float*)d_in[12];

    uint8_t* ws = (uint8_t*)d_ws;
    uint4* w1b = (uint4*)(ws + WS_W1B);
    uint4* w2b = (uint4*)(ws + WS_W2B);
    float* bnc = (float*)(ws + WS_BN);
    uint4* bits2 = (uint4*)(ws + WS_BITS2);
    uint4* bits1 = (uint4*)(ws + WS_BITS1);
    uint2* res1 = (uint2*)(ws + WS_RES1);
    float* outp = (float*)d_out;

    hipLaunchKernelGGL(binpack_kernel, dim3(392 * 5 + 10), dim3(256), 0, stream,
                       x, mv0, mv1, w1, w2, g1, b1, m1, v1, g2, b2, m2, v2,
                       bits1, bits2, w1b, w2b, bnc, outp);
    hipLaunchKernelGGL(conv1_kernel, dim3(224 * 16), dim3(448), 0, stream,
                       x, w1b, bnc, mv1, bits1, bits2, res1, outp);
    hipLaunchKernelGGL(conv2_kernel, dim3(224 * 16), dim3(448), 0, stream,
                       x, w2b, bnc, mv0, bits2, res1, outp);
}

// Round 15
// 107.076 us; speedup vs baseline: 7.7232x; 1.0828x over previous
//
#include <hip/hip_runtime.h>
#include <stdint.h>

// BasicBlock: binarized ShuffleNet-style block via XNOR-popcount conv.
// conv = 128*nv - 2*popcount(bits_in ^ bits_w) over valid taps (exact integers).
// R14: LDS-free conv kernels. bits arrays are L2/L3-resident (1.6MB), so the
// window is read DIRECTLY from global (coalesced per tap); clamped addresses +
// existing masks handle borders. 256-thread blocks, no barrier -> occupancy
// free to reach 8 waves/SIMD. Channel-outer + SGPR weights (R13, proven).

#define HH 56
#define WW 56
#define HW 3136
#define NBATCH 32
#define NPX (NBATCH * HW)   // 100352

// ws layout (bytes)
#define WS_W1B   0u          // 128*9 uint4 = 18432
#define WS_W2B   18432u      // 18432
#define WS_BN    36864u      // floats inv1[128] c1[128] inv2[128] c2[128]
#define WS_BITS2 40960u      // uint4 per pixel: 100352*16 = 1605632
#define WS_BITS1 1646592u    // 1605632
#define WS_RES1  3252224u    // int8 [8 groups][NPX][8B] = 6422528 (end 9.7MB)

#define PC(a,b) (__popc((a).x ^ (b).x) + __popc((a).y ^ (b).y) + \
                 __popc((a).z ^ (b).z) + __popc((a).w ^ (b).w))

// Kernel A: blocks 0..1959: per-pixel packing + pass-through planes.
// Blocks 1960..1969: weight binarization + bn constant prep.
__global__ __launch_bounds__(256) void binpack_kernel(
    const float* __restrict__ x, const float* __restrict__ move0,
    const float* __restrict__ move1,
    const float* __restrict__ w1, const float* __restrict__ w2,
    const float* __restrict__ g1, const float* __restrict__ b1,
    const float* __restrict__ m1, const float* __restrict__ v1,
    const float* __restrict__ g2, const float* __restrict__ b2,
    const float* __restrict__ m2, const float* __restrict__ v2,
    uint4* __restrict__ bits1, uint4* __restrict__ bits2,
    uint4* __restrict__ w1b, uint4* __restrict__ w2b, float* __restrict__ bnc,
    float* __restrict__ out)
{
    if (blockIdx.x >= 1960) {           // ---- prep section ----
        int t = (blockIdx.x - 1960) * 256 + threadIdx.x;
        if (t < 2304) {
            const float* w = (t < 1152) ? w1 : w2;
            uint4* dst = (t < 1152) ? w1b : w2b;
            int tt = (t < 1152) ? t : t - 1152;
            int o = tt / 9, tap = tt % 9;
            const float* wp = w + (size_t)o * 1152 + tap;
            uint32_t b[4];
            #pragma unroll
            for (int wd = 0; wd < 4; ++wd) {
                uint32_t acc = 0;
                #pragma unroll
                for (int bi = 0; bi < 32; ++bi) {
                    float wv = wp[(size_t)(wd * 32 + bi) * 9];
                    acc |= (wv >= 0.0f ? 1u : 0u) << bi;
                }
                b[wd] = acc;
            }
            dst[o * 9 + tap] = make_uint4(b[0], b[1], b[2], b[3]);
        } else if (t < 2432) {
            int c = t - 2304;
            float i1 = __fdiv_rn(g1[c], __fsqrt_rn(__fadd_rn(v1[c], 1e-5f)));
            bnc[c]       = i1;
            bnc[128 + c] = __fsub_rn(b1[c], __fmul_rn(m1[c], i1));
            float i2 = __fdiv_rn(g2[c], __fsqrt_rn(__fadd_rn(v2[c], 1e-5f)));
            bnc[256 + c] = i2;
            bnc[384 + c] = __fsub_rn(b2[c], __fmul_rn(m2[c], i2));
        }
        return;
    }

    const int g = blockIdx.x / 392;
    const int px = (blockIdx.x % 392) * 256 + threadIdx.x;   // < NPX exactly
    const int n = px / HW, poff = px % HW;
    const float* xn = x + (size_t)n * 256 * HW + poff;

    if (g < 2) {
        const int cb = g * 64;
        uint32_t w0 = 0, w1v = 0;
        #pragma unroll
        for (int c = 0; c < 32; ++c)
            w0 |= (xn[(size_t)(cb + c) * HW] >= 0.0f ? 1u : 0u) << c;
        #pragma unroll
        for (int c = 0; c < 32; ++c)
            w1v |= (xn[(size_t)(cb + 32 + c) * HW] >= 0.0f ? 1u : 0u) << c;
        ((uint2*)&bits1[px])[g] = make_uint2(w0, w1v);
    } else if (g == 2) {
        uint32_t w0 = 0, w1v = 0, w2v = 0, w3 = 0;
        #pragma unroll
        for (int k = 0; k < 64; ++k) {
            float s = __fadd_rn(xn[(size_t)(128 + k) * HW], move0[k]);
            uint32_t m = (s >= 0.0f ? 1u : 0u) << (2 * (k & 15) + 1);
            if ((k >> 4) == 0) w0 |= m; else if ((k >> 4) == 1) w1v |= m;
            else if ((k >> 4) == 2) w2v |= m; else w3 |= m;
        }
        bits2[px] = make_uint4(w0, w1v, w2v, w3);
    } else {
        const int mb = (g - 3) * 32;
        for (int mm = 0; mm < 32; ++mm) {
            int m = mb + mm;
            float v = __fadd_rn(__fadd_rn(xn[(size_t)(192 + m) * HW],
                                          move0[64 + m]), move1[2 * m + 1]);
            out[(size_t)(n * 256 + 4 * m + 3) * HW + poff] = v;
        }
    }
}

// Conv kernels: 256 threads, one pixel per thread, LDS-free.
// Window read directly from bits array (L2/L3-hot); row-clamped addresses,
// masks zero invalid taps. b: js = b & 15 (j = 8js + jj), p = b >> 4.

__device__ __forceinline__ int clampi(int v, int lo, int hi) {
    return v < lo ? lo : (v > hi ? hi : v);
}

// Kernel B: conv1.
//  js<8  (j<64): bits2 even bits via uint16 slot js + res1 uint2.
//  js>=8 (j>=64): out planes 4m+1, m = j-64.
__global__ __launch_bounds__(256) void conv1_kernel(
    const float* __restrict__ x, const uint4* __restrict__ w1b,
    const float* __restrict__ bnc, const float* __restrict__ move1,
    const uint4* __restrict__ bits1, uint4* __restrict__ bits2,
    uint2* __restrict__ res1, float* __restrict__ out)
{
    const int b = blockIdx.x;
    const int js = b & 15;
    const int px = (b >> 4) * 256 + threadIdx.x;
    const int n = px / HW, poff = px % HW;

    const float* xn = x + (size_t)n * 256 * HW;
    const size_t pxi = (size_t)px;
    const uint4* __restrict__ wjs = w1b + js * 72;   // wave-uniform base

    // batched preloads: 8 residual streams + old idle bits
    float rres[8];
    #pragma unroll
    for (int jj = 0; jj < 8; ++jj)
        rres[jj] = xn[(size_t)(js * 8 + jj) * HW + poff];
    uint32_t old16 = 0;
    if (js < 8) old16 = ((const uint16_t*)(bits2 + pxi))[js];

    const int row = poff / WW, col = poff % WW;
    const int rok0 = (row >= 1), rok2 = (row <= HH - 2);
    const int cok0 = (col >= 1), cok2 = (col <= WW - 2);
    const uint32_t rs0 = rok0 ? ~0u : 0u, rs2 = rok2 ? ~0u : 0u;
    const uint32_t csL = cok0 ? ~0u : 0u, csR = cok2 ? ~0u : 0u;
    const int nvbase = ((1 + rok0 + rok2) * (1 + cok0 + cok2)) << 7;

    // window direct from global, row-clamped (masks kill invalid taps)
    const uint4* bsrc = bits1 + (size_t)n * HW;
    const uint4 i00 = bsrc[clampi(poff - 57, 0, HW - 1)];
    const uint4 i01 = bsrc[clampi(poff - 56, 0, HW - 1)];
    const uint4 i02 = bsrc[clampi(poff - 55, 0, HW - 1)];
    const uint4 i10 = bsrc[clampi(poff - 1, 0, HW - 1)];
    const uint4 i11 = bsrc[poff];
    const uint4 i12 = bsrc[clampi(poff + 1, 0, HW - 1)];
    const uint4 i20 = bsrc[clampi(poff + 55, 0, HW - 1)];
    const uint4 i21 = bsrc[clampi(poff + 56, 0, HW - 1)];
    const uint4 i22 = bsrc[clampi(poff + 57, 0, HW - 1)];

    uint32_t bw = old16;
    uint32_t q0 = 0, q1 = 0;        // 8 int8 res1 bytes

    #pragma unroll
    for (int jj = 0; jj < 8; ++jj) {
        const int j = js * 8 + jj;
        int acc = 0;
        acc += PC(wjs[jj * 9 + 0], i00) & (int)(rs0 & csL);
        acc += PC(wjs[jj * 9 + 1], i01) & (int)rs0;
        acc += PC(wjs[jj * 9 + 2], i02) & (int)(rs0 & csR);
        acc += PC(wjs[jj * 9 + 3], i10) & (int)csL;
        acc += PC(wjs[jj * 9 + 4], i11);
        acc += PC(wjs[jj * 9 + 5], i12) & (int)csR;
        acc += PC(wjs[jj * 9 + 6], i20) & (int)(rs2 & csL);
        acc += PC(wjs[jj * 9 + 7], i21) & (int)rs2;
        acc += PC(wjs[jj * 9 + 8], i22) & (int)(rs2 & csR);
        float convf = (float)(nvbase - (acc << 1));
        float bno = __fadd_rn(__fmul_rn(convf, bnc[j]), bnc[128 + j]);
        float v2 = __fadd_rn(bno, rres[jj]);
        float vc = fminf(fmaxf(v2, -1.0f), 1.0f);
        if (js < 8) {
            bw |= (v2 >= 0.0f ? 1u : 0u) << (2 * jj);
            uint32_t q = (uint32_t)(uint8_t)(int8_t)__float2int_rn(
                __fmul_rn(vc, 127.0f));
            uint32_t sh = 8 * (jj & 3);
            if (jj < 4) q0 |= q << sh; else q1 |= q << sh;
        } else {
            int m = j - 64;
            out[(size_t)(n * 256 + 4 * m + 1) * HW + poff] =
                __fadd_rn(vc, move1[2 * m]);
        }
    }
    if (js < 8) {
        res1[(size_t)js * NPX + pxi] = make_uint2(q0, q1);
        ((uint16_t*)(bits2 + pxi))[js] = (uint16_t)bw;
    }
}

// Kernel C: conv2. out plane 2j.
__global__ __launch_bounds__(256) void conv2_kernel(
    const float* __restrict__ x, const uint4* __restrict__ w2b,
    const float* __restrict__ bnc, const float* __restrict__ move0,
    const uint4* __restrict__ bits2, const uint2* __restrict__ res1,
    float* __restrict__ out)
{
    const int b = blockIdx.x;
    const int js = b & 15;
    const int px = (b >> 4) * 256 + threadIdx.x;
    const int n = px / HW, poff = px % HW;

    const float* xn = x + (size_t)n * 256 * HW;
    const size_t pxi = (size_t)px;
    const uint4* __restrict__ wjs = w2b + js * 72;   // wave-uniform base

    // batched per-thread global loads (4 int8 even-j residuals + 4 idle floats)
    const uint32_t rq = ((const uint32_t*)(res1 + (size_t)(js >> 1) * NPX + pxi))[js & 1];
    float ro[4];
    #pragma unroll
    for (int k = 0; k < 4; ++k)
        ro[k] = xn[(size_t)(128 + js * 4 + k) * HW + poff];

    const int row = poff / WW, col = poff % WW;
    const int rok0 = (row >= 1), rok2 = (row <= HH - 2);
    const int cok0 = (col >= 1), cok2 = (col <= WW - 2);
    const uint32_t rs0 = rok0 ? ~0u : 0u, rs2 = rok2 ? ~0u : 0u;
    const uint32_t csL = cok0 ? ~0u : 0u, csR = cok2 ? ~0u : 0u;
    const int nvbase = ((1 + rok0 + rok2) * (1 + cok0 + cok2)) << 7;

    const uint4* bsrc = bits2 + (size_t)n * HW;
    const uint4 i00 = bsrc[clampi(poff - 57, 0, HW - 1)];
    const uint4 i01 = bsrc[clampi(poff - 56, 0, HW - 1)];
    const uint4 i02 = bsrc[clampi(poff - 55, 0, HW - 1)];
    const uint4 i10 = bsrc[clampi(poff - 1, 0, HW - 1)];
    const uint4 i11 = bsrc[poff];
    const uint4 i12 = bsrc[clampi(poff + 1, 0, HW - 1)];
    const uint4 i20 = bsrc[clampi(poff + 55, 0, HW - 1)];
    const uint4 i21 = bsrc[clampi(poff + 56, 0, HW - 1)];
    const uint4 i22 = bsrc[clampi(poff + 57, 0, HW - 1)];

    #pragma unroll
    for (int jj = 0; jj < 8; ++jj) {
        const int j = js * 8 + jj;
        int acc = 0;
        acc += PC(wjs[jj * 9 + 0], i00) & (int)(rs0 & csL);
        acc += PC(wjs[jj * 9 + 1], i01) & (int)rs0;
        acc += PC(wjs[jj * 9 + 2], i02) & (int)(rs0 & csR);
        acc += PC(wjs[jj * 9 + 3], i10) & (int)csL;
        acc += PC(wjs[jj * 9 + 4], i11);
        acc += PC(wjs[jj * 9 + 5], i12) & (int)csR;
        acc += PC(wjs[jj * 9 + 6], i20) & (int)(rs2 & csL);
        acc += PC(wjs[jj * 9 + 7], i21) & (int)rs2;
        acc += PC(wjs[jj * 9 + 8], i22) & (int)(rs2 & csR);
        float convf = (float)(nvbase - (acc << 1));
        float bno = __fadd_rn(__fmul_rn(convf, bnc[256 + j]), bnc[384 + j]);
        float resv;
        if (jj & 1) {
            resv = __fadd_rn(ro[jj >> 1], move0[j >> 1]);
        } else {
            int8_t q = (int8_t)(uint8_t)(rq >> (8 * (jj >> 1)));
            resv = __fmul_rn(__int2float_rn((int)q), 1.0f / 127.0f);
        }
        float v2 = __fadd_rn(bno, resv);
        float vc = fminf(fmaxf(v2, -1.0f), 1.0f);
        out[(size_t)(n * 256 + 2 * j) * HW + poff] = vc;
    }
}

extern "C" void kernel_launch(void* const* d_in, const int* in_sizes, int n_in,
                              void* d_out, int out_size, void* d_ws, size_t ws_size,
                              hipStream_t stream)
{
    const float* x   = (const float*)d_in[0];
    const float* w1  = (const float*)d_in[1];
    const float* w2  = (const float*)d_in[2];
    const float* g1  = (const float*)d_in[3];
    const float* b1  = (const float*)d_in[4];
    const float* m1  = (const float*)d_in[5];
    const float* v1  = (const float*)d_in[6];
    const float* g2  = (const float*)d_in[7];
    const float* b2  = (const float*)d_in[8];
    const float* m2  = (const float*)d_in[9];
    const float* v2  = (const float*)d_in[10];
    const float* mv0 = (const float*)d_in[11];
    const float* mv1 = (const float*)d_in[12];

    uint8_t* ws = (uint8_t*)d_ws;
    uint4* w1b = (uint4*)(ws + WS_W1B);
    uint4* w2b = (uint4*)(ws + WS_W2B);
    float* bnc = (float*)(ws + WS_BN);
    uint4* bits2 = (uint4*)(ws + WS_BITS2);
    uint4* bits1 = (uint4*)(ws + WS_BITS1);
    uint2* res1 = (uint2*)(ws + WS_RES1);
    float* outp = (float*)d_out;

    hipLaunchKernelGGL(binpack_kernel, dim3(392 * 5 + 10), dim3(256), 0, stream,
                       x, mv0, mv1, w1, w2, g1, b1, m1, v1, g2, b2, m2, v2,
                       bits1, bits2, w1b, w2b, bnc, outp);
    hipLaunchKernelGGL(conv1_kernel, dim3(392 * 16), dim3(256), 0, stream,
                       x, w1b, bnc, mv1, bits1, bits2, res1, outp);
    hipLaunchKernelGGL(conv2_kernel, dim3(392 * 16), dim3(256), 0, stream,
                       x, w2b, bnc, mv0, bits2, res1, outp);
}

// Round 16
// 105.322 us; speedup vs baseline: 7.8518x; 1.0166x over previous
//
#include <hip/hip_runtime.h>
#include <stdint.h>

// BasicBlock: binarized ShuffleNet-style block via XNOR-popcount conv.
// conv = 128*nv - 2*popcount(bits_in ^ bits_w) over valid taps (exact integers).
// R16: R15 (LDS-free, channel-outer, SGPR weights) + NONTEMPORAL stores for
// all `out` writes. out (103MB) is write-once/never-read; keeping it out of
// L2/L3 lets x (103MB) + ws stay L3-resident for the convs' residual re-reads.

#define HH 56
#define WW 56
#define HW 3136
#define NBATCH 32
#define NPX (NBATCH * HW)   // 100352

// ws layout (bytes)
#define WS_W1B   0u          // 128*9 uint4 = 18432
#define WS_W2B   18432u      // 18432
#define WS_BN    36864u      // floats inv1[128] c1[128] inv2[128] c2[128]
#define WS_BITS2 40960u      // uint4 per pixel: 100352*16 = 1605632
#define WS_BITS1 1646592u    // 1605632
#define WS_RES1  3252224u    // int8 [8 groups][NPX][8B] = 6422528 (end 9.7MB)

#define PC(a,b) (__popc((a).x ^ (b).x) + __popc((a).y ^ (b).y) + \
                 __popc((a).z ^ (b).z) + __popc((a).w ^ (b).w))

// Kernel A: blocks 0..1959: per-pixel packing + pass-through planes.
// Blocks 1960..1969: weight binarization + bn constant prep.
__global__ __launch_bounds__(256) void binpack_kernel(
    const float* __restrict__ x, const float* __restrict__ move0,
    const float* __restrict__ move1,
    const float* __restrict__ w1, const float* __restrict__ w2,
    const float* __restrict__ g1, const float* __restrict__ b1,
    const float* __restrict__ m1, const float* __restrict__ v1,
    const float* __restrict__ g2, const float* __restrict__ b2,
    const float* __restrict__ m2, const float* __restrict__ v2,
    uint4* __restrict__ bits1, uint4* __restrict__ bits2,
    uint4* __restrict__ w1b, uint4* __restrict__ w2b, float* __restrict__ bnc,
    float* __restrict__ out)
{
    if (blockIdx.x >= 1960) {           // ---- prep section ----
        int t = (blockIdx.x - 1960) * 256 + threadIdx.x;
        if (t < 2304) {
            const float* w = (t < 1152) ? w1 : w2;
            uint4* dst = (t < 1152) ? w1b : w2b;
            int tt = (t < 1152) ? t : t - 1152;
            int o = tt / 9, tap = tt % 9;
            const float* wp = w + (size_t)o * 1152 + tap;
            uint32_t b[4];
            #pragma unroll
            for (int wd = 0; wd < 4; ++wd) {
                uint32_t acc = 0;
                #pragma unroll
                for (int bi = 0; bi < 32; ++bi) {
                    float wv = wp[(size_t)(wd * 32 + bi) * 9];
                    acc |= (wv >= 0.0f ? 1u : 0u) << bi;
                }
                b[wd] = acc;
            }
            dst[o * 9 + tap] = make_uint4(b[0], b[1], b[2], b[3]);
        } else if (t < 2432) {
            int c = t - 2304;
            float i1 = __fdiv_rn(g1[c], __fsqrt_rn(__fadd_rn(v1[c], 1e-5f)));
            bnc[c]       = i1;
            bnc[128 + c] = __fsub_rn(b1[c], __fmul_rn(m1[c], i1));
            float i2 = __fdiv_rn(g2[c], __fsqrt_rn(__fadd_rn(v2[c], 1e-5f)));
            bnc[256 + c] = i2;
            bnc[384 + c] = __fsub_rn(b2[c], __fmul_rn(m2[c], i2));
        }
        return;
    }

    const int g = blockIdx.x / 392;
    const int px = (blockIdx.x % 392) * 256 + threadIdx.x;   // < NPX exactly
    const int n = px / HW, poff = px % HW;
    const float* xn = x + (size_t)n * 256 * HW + poff;

    if (g < 2) {
        const int cb = g * 64;
        uint32_t w0 = 0, w1v = 0;
        #pragma unroll
        for (int c = 0; c < 32; ++c)
            w0 |= (xn[(size_t)(cb + c) * HW] >= 0.0f ? 1u : 0u) << c;
        #pragma unroll
        for (int c = 0; c < 32; ++c)
            w1v |= (xn[(size_t)(cb + 32 + c) * HW] >= 0.0f ? 1u : 0u) << c;
        ((uint2*)&bits1[px])[g] = make_uint2(w0, w1v);
    } else if (g == 2) {
        uint32_t w0 = 0, w1v = 0, w2v = 0, w3 = 0;
        #pragma unroll
        for (int k = 0; k < 64; ++k) {
            float s = __fadd_rn(xn[(size_t)(128 + k) * HW], move0[k]);
            uint32_t m = (s >= 0.0f ? 1u : 0u) << (2 * (k & 15) + 1);
            if ((k >> 4) == 0) w0 |= m; else if ((k >> 4) == 1) w1v |= m;
            else if ((k >> 4) == 2) w2v |= m; else w3 |= m;
        }
        bits2[px] = make_uint4(w0, w1v, w2v, w3);
    } else {
        const int mb = (g - 3) * 32;
        for (int mm = 0; mm < 32; ++mm) {
            int m = mb + mm;
            float v = __fadd_rn(__fadd_rn(xn[(size_t)(192 + m) * HW],
                                          move0[64 + m]), move1[2 * m + 1]);
            __builtin_nontemporal_store(v,
                &out[(size_t)(n * 256 + 4 * m + 3) * HW + poff]);
        }
    }
}

// Conv kernels: 256 threads, one pixel per thread, LDS-free.
// Window read directly from bits array (L2/L3-hot); row-clamped addresses,
// masks zero invalid taps. b: js = b & 15 (j = 8js + jj), p = b >> 4.

__device__ __forceinline__ int clampi(int v, int lo, int hi) {
    return v < lo ? lo : (v > hi ? hi : v);
}

// Kernel B: conv1.
//  js<8  (j<64): bits2 even bits via uint16 slot js + res1 uint2.
//  js>=8 (j>=64): out planes 4m+1, m = j-64.
__global__ __launch_bounds__(256) void conv1_kernel(
    const float* __restrict__ x, const uint4* __restrict__ w1b,
    const float* __restrict__ bnc, const float* __restrict__ move1,
    const uint4* __restrict__ bits1, uint4* __restrict__ bits2,
    uint2* __restrict__ res1, float* __restrict__ out)
{
    const int b = blockIdx.x;
    const int js = b & 15;
    const int px = (b >> 4) * 256 + threadIdx.x;
    const int n = px / HW, poff = px % HW;

    const float* xn = x + (size_t)n * 256 * HW;
    const size_t pxi = (size_t)px;
    const uint4* __restrict__ wjs = w1b + js * 72;   // wave-uniform base

    // batched preloads: 8 residual streams + old idle bits
    float rres[8];
    #pragma unroll
    for (int jj = 0; jj < 8; ++jj)
        rres[jj] = xn[(size_t)(js * 8 + jj) * HW + poff];
    uint32_t old16 = 0;
    if (js < 8) old16 = ((const uint16_t*)(bits2 + pxi))[js];

    const int row = poff / WW, col = poff % WW;
    const int rok0 = (row >= 1), rok2 = (row <= HH - 2);
    const int cok0 = (col >= 1), cok2 = (col <= WW - 2);
    const uint32_t rs0 = rok0 ? ~0u : 0u, rs2 = rok2 ? ~0u : 0u;
    const uint32_t csL = cok0 ? ~0u : 0u, csR = cok2 ? ~0u : 0u;
    const int nvbase = ((1 + rok0 + rok2) * (1 + cok0 + cok2)) << 7;

    // window direct from global, row-clamped (masks kill invalid taps)
    const uint4* bsrc = bits1 + (size_t)n * HW;
    const uint4 i00 = bsrc[clampi(poff - 57, 0, HW - 1)];
    const uint4 i01 = bsrc[clampi(poff - 56, 0, HW - 1)];
    const uint4 i02 = bsrc[clampi(poff - 55, 0, HW - 1)];
    const uint4 i10 = bsrc[clampi(poff - 1, 0, HW - 1)];
    const uint4 i11 = bsrc[poff];
    const uint4 i12 = bsrc[clampi(poff + 1, 0, HW - 1)];
    const uint4 i20 = bsrc[clampi(poff + 55, 0, HW - 1)];
    const uint4 i21 = bsrc[clampi(poff + 56, 0, HW - 1)];
    const uint4 i22 = bsrc[clampi(poff + 57, 0, HW - 1)];

    uint32_t bw = old16;
    uint32_t q0 = 0, q1 = 0;        // 8 int8 res1 bytes

    #pragma unroll
    for (int jj = 0; jj < 8; ++jj) {
        const int j = js * 8 + jj;
        int acc = 0;
        acc += PC(wjs[jj * 9 + 0], i00) & (int)(rs0 & csL);
        acc += PC(wjs[jj * 9 + 1], i01) & (int)rs0;
        acc += PC(wjs[jj * 9 + 2], i02) & (int)(rs0 & csR);
        acc += PC(wjs[jj * 9 + 3], i10) & (int)csL;
        acc += PC(wjs[jj * 9 + 4], i11);
        acc += PC(wjs[jj * 9 + 5], i12) & (int)csR;
        acc += PC(wjs[jj * 9 + 6], i20) & (int)(rs2 & csL);
        acc += PC(wjs[jj * 9 + 7], i21) & (int)rs2;
        acc += PC(wjs[jj * 9 + 8], i22) & (int)(rs2 & csR);
        float convf = (float)(nvbase - (acc << 1));
        float bno = __fadd_rn(__fmul_rn(convf, bnc[j]), bnc[128 + j]);
        float v2 = __fadd_rn(bno, rres[jj]);
        float vc = fminf(fmaxf(v2, -1.0f), 1.0f);
        if (js < 8) {
            bw |= (v2 >= 0.0f ? 1u : 0u) << (2 * jj);
            uint32_t q = (uint32_t)(uint8_t)(int8_t)__float2int_rn(
                __fmul_rn(vc, 127.0f));
            uint32_t sh = 8 * (jj & 3);
            if (jj < 4) q0 |= q << sh; else q1 |= q << sh;
        } else {
            int m = j - 64;
            __builtin_nontemporal_store(__fadd_rn(vc, move1[2 * m]),
                &out[(size_t)(n * 256 + 4 * m + 1) * HW + poff]);
        }
    }
    if (js < 8) {
        res1[(size_t)js * NPX + pxi] = make_uint2(q0, q1);
        ((uint16_t*)(bits2 + pxi))[js] = (uint16_t)bw;
    }
}

// Kernel C: conv2. out plane 2j.
__global__ __launch_bounds__(256) void conv2_kernel(
    const float* __restrict__ x, const uint4* __restrict__ w2b,
    const float* __restrict__ bnc, const float* __restrict__ move0,
    const uint4* __restrict__ bits2, const uint2* __restrict__ res1,
    float* __restrict__ out)
{
    const int b = blockIdx.x;
    const int js = b & 15;
    const int px = (b >> 4) * 256 + threadIdx.x;
    const int n = px / HW, poff = px % HW;

    const float* xn = x + (size_t)n * 256 * HW;
    const size_t pxi = (size_t)px;
    const uint4* __restrict__ wjs = w2b + js * 72;   // wave-uniform base

    // batched per-thread global loads (4 int8 even-j residuals + 4 idle floats)
    const uint32_t rq = ((const uint32_t*)(res1 + (size_t)(js >> 1) * NPX + pxi))[js & 1];
    float ro[4];
    #pragma unroll
    for (int k = 0; k < 4; ++k)
        ro[k] = xn[(size_t)(128 + js * 4 + k) * HW + poff];

    const int row = poff / WW, col = poff % WW;
    const int rok0 = (row >= 1), rok2 = (row <= HH - 2);
    const int cok0 = (col >= 1), cok2 = (col <= WW - 2);
    const uint32_t rs0 = rok0 ? ~0u : 0u, rs2 = rok2 ? ~0u : 0u;
    const uint32_t csL = cok0 ? ~0u : 0u, csR = cok2 ? ~0u : 0u;
    const int nvbase = ((1 + rok0 + rok2) * (1 + cok0 + cok2)) << 7;

    const uint4* bsrc = bits2 + (size_t)n * HW;
    const uint4 i00 = bsrc[clampi(poff - 57, 0, HW - 1)];
    const uint4 i01 = bsrc[clampi(poff - 56, 0, HW - 1)];
    const uint4 i02 = bsrc[clampi(poff - 55, 0, HW - 1)];
    const uint4 i10 = bsrc[clampi(poff - 1, 0, HW - 1)];
    const uint4 i11 = bsrc[poff];
    const uint4 i12 = bsrc[clampi(poff + 1, 0, HW - 1)];
    const uint4 i20 = bsrc[clampi(poff + 55, 0, HW - 1)];
    const uint4 i21 = bsrc[clampi(poff + 56, 0, HW - 1)];
    const uint4 i22 = bsrc[clampi(poff + 57, 0, HW - 1)];

    #pragma unroll
    for (int jj = 0; jj < 8; ++jj) {
        const int j = js * 8 + jj;
        int acc = 0;
        acc += PC(wjs[jj * 9 + 0], i00) & (int)(rs0 & csL);
        acc += PC(wjs[jj * 9 + 1], i01) & (int)rs0;
        acc += PC(wjs[jj * 9 + 2], i02) & (int)(rs0 & csR);
        acc += PC(wjs[jj * 9 + 3], i10) & (int)csL;
        acc += PC(wjs[jj * 9 + 4], i11);
        acc += PC(wjs[jj * 9 + 5], i12) & (int)csR;
        acc += PC(wjs[jj * 9 + 6], i20) & (int)(rs2 & csL);
        acc += PC(wjs[jj * 9 + 7], i21) & (int)rs2;
        acc += PC(wjs[jj * 9 + 8], i22) & (int)(rs2 & csR);
        float convf = (float)(nvbase - (acc << 1));
        float bno = __fadd_rn(__fmul_rn(convf, bnc[256 + j]), bnc[384 + j]);
        float resv;
        if (jj & 1) {
            resv = __fadd_rn(ro[jj >> 1], move0[j >> 1]);
        } else {
            int8_t q = (int8_t)(uint8_t)(rq >> (8 * (jj >> 1)));
            resv = __fmul_rn(__int2float_rn((int)q), 1.0f / 127.0f);
        }
        float v2 = __fadd_rn(bno, resv);
        float vc = fminf(fmaxf(v2, -1.0f), 1.0f);
        __builtin_nontemporal_store(vc,
            &out[(size_t)(n * 256 + 2 * j) * HW + poff]);
    }
}

extern "C" void kernel_launch(void* const* d_in, const int* in_sizes, int n_in,
                              void* d_out, int out_size, void* d_ws, size_t ws_size,
                              hipStream_t stream)
{
    const float* x   = (const float*)d_in[0];
    const float* w1  = (const float*)d_in[1];
    const float* w2  = (const float*)d_in[2];
    const float* g1  = (const float*)d_in[3];
    const float* b1  = (const float*)d_in[4];
    const float* m1  = (const float*)d_in[5];
    const float* v1  = (const float*)d_in[6];
    const float* g2  = (const float*)d_in[7];
    const float* b2  = (const float*)d_in[8];
    const float* m2  = (const float*)d_in[9];
    const float* v2  = (const float*)d_in[10];
    const float* mv0 = (const float*)d_in[11];
    const float* mv1 = (const float*)d_in[12];

    uint8_t* ws = (uint8_t*)d_ws;
    uint4* w1b = (uint4*)(ws + WS_W1B);
    uint4* w2b = (uint4*)(ws + WS_W2B);
    float* bnc = (float*)(ws + WS_BN);
    uint4* bits2 = (uint4*)(ws + WS_BITS2);
    uint4* bits1 = (uint4*)(ws + WS_BITS1);
    uint2* res1 = (uint2*)(ws + WS_RES1);
    float* outp = (float*)d_out;

    hipLaunchKernelGGL(binpack_kernel, dim3(392 * 5 + 10), dim3(256), 0, stream,
                       x, mv0, mv1, w1, w2, g1, b1, m1, v1, g2, b2, m2, v2,
                       bits1, bits2, w1b, w2b, bnc, outp);
    hipLaunchKernelGGL(conv1_kernel, dim3(392 * 16), dim3(256), 0, stream,
                       x, w1b, bnc, mv1, bits1, bits2, res1, outp);
    hipLaunchKernelGGL(conv2_kernel, dim3(392 * 16), dim3(256), 0, stream,
                       x, w2b, bnc, mv0, bits2, res1, outp);
}

// Round 17
// 98.737 us; speedup vs baseline: 8.3754x; 1.0667x over previous
//
#include <hip/hip_runtime.h>
#include <stdint.h>

// BasicBlock: binarized ShuffleNet-style block via XNOR-popcount conv.
// conv = 128*nv - 2*popcount(bits_in ^ bits_w) over valid taps (exact integers).
// R17: shrink the serial binpack stage to bits1-only (+prep); idle odd bits
// computed inside conv1 (kills the bits2 RMW dependency); pass-through planes
// folded into conv2. Extra loads hide in the convs' latency stalls.

#define HH 56
#define WW 56
#define HW 3136
#define NBATCH 32
#define NPX (NBATCH * HW)   // 100352

// ws layout (bytes)
#define WS_W1B   0u          // 128*9 uint4 = 18432
#define WS_W2B   18432u      // 18432
#define WS_BN    36864u      // floats inv1[128] c1[128] inv2[128] c2[128]
#define WS_BITS2 40960u      // uint4 per pixel: 100352*16 = 1605632
#define WS_BITS1 1646592u    // 1605632
#define WS_RES1  3252224u    // int8 [8 groups][NPX][8B] = 6422528 (end 9.7MB)

#define PC(a,b) (__popc((a).x ^ (b).x) + __popc((a).y ^ (b).y) + \
                 __popc((a).z ^ (b).z) + __popc((a).w ^ (b).w))

// Kernel A: blocks 0..783: bits1 packing (g = b/392: word pair g).
// Blocks 784..793: weight binarization + bn constant prep.
__global__ __launch_bounds__(256) void binpack_kernel(
    const float* __restrict__ x,
    const float* __restrict__ w1, const float* __restrict__ w2,
    const float* __restrict__ g1, const float* __restrict__ b1,
    const float* __restrict__ m1, const float* __restrict__ v1,
    const float* __restrict__ g2, const float* __restrict__ b2,
    const float* __restrict__ m2, const float* __restrict__ v2,
    uint4* __restrict__ bits1,
    uint4* __restrict__ w1b, uint4* __restrict__ w2b, float* __restrict__ bnc)
{
    if (blockIdx.x >= 784) {            // ---- prep section ----
        int t = (blockIdx.x - 784) * 256 + threadIdx.x;
        if (t < 2304) {
            const float* w = (t < 1152) ? w1 : w2;
            uint4* dst = (t < 1152) ? w1b : w2b;
            int tt = (t < 1152) ? t : t - 1152;
            int o = tt / 9, tap = tt % 9;
            const float* wp = w + (size_t)o * 1152 + tap;
            uint32_t b[4];
            #pragma unroll
            for (int wd = 0; wd < 4; ++wd) {
                uint32_t acc = 0;
                #pragma unroll
                for (int bi = 0; bi < 32; ++bi) {
                    float wv = wp[(size_t)(wd * 32 + bi) * 9];
                    acc |= (wv >= 0.0f ? 1u : 0u) << bi;
                }
                b[wd] = acc;
            }
            dst[o * 9 + tap] = make_uint4(b[0], b[1], b[2], b[3]);
        } else if (t < 2432) {
            int c = t - 2304;
            float i1 = __fdiv_rn(g1[c], __fsqrt_rn(__fadd_rn(v1[c], 1e-5f)));
            bnc[c]       = i1;
            bnc[128 + c] = __fsub_rn(b1[c], __fmul_rn(m1[c], i1));
            float i2 = __fdiv_rn(g2[c], __fsqrt_rn(__fadd_rn(v2[c], 1e-5f)));
            bnc[256 + c] = i2;
            bnc[384 + c] = __fsub_rn(b2[c], __fmul_rn(m2[c], i2));
        }
        return;
    }

    const int g = blockIdx.x / 392;     // 0: ch 0..63, 1: ch 64..127
    const int px = (blockIdx.x % 392) * 256 + threadIdx.x;   // < NPX exactly
    const int n = px / HW, poff = px % HW;
    const float* xn = x + (size_t)n * 256 * HW + poff;

    const int cb = g * 64;
    uint32_t w0 = 0, w1v = 0;
    #pragma unroll
    for (int c = 0; c < 32; ++c)
        w0 |= (xn[(size_t)(cb + c) * HW] >= 0.0f ? 1u : 0u) << c;
    #pragma unroll
    for (int c = 0; c < 32; ++c)
        w1v |= (xn[(size_t)(cb + 32 + c) * HW] >= 0.0f ? 1u : 0u) << c;
    ((uint2*)&bits1[px])[g] = make_uint2(w0, w1v);
}

// Conv kernels: 256 threads, one pixel per thread, LDS-free.
// Window read directly from bits array (L2/L3-hot); row-clamped addresses,
// masks zero invalid taps. b: js = b & 15 (j = 8js + jj), p = b >> 4.

__device__ __forceinline__ int clampi(int v, int lo, int hi) {
    return v < lo ? lo : (v > hi ? hi : v);
}

// Kernel B: conv1.
//  js<8  (j<64): full bits2 uint16 slot js (even bits = conv sign, odd bits =
//                sign(x[128+8js+jj]+move0), computed here) + res1 uint2.
//  js>=8 (j>=64): out planes 4m+1, m = j-64.
__global__ __launch_bounds__(256) void conv1_kernel(
    const float* __restrict__ x, const uint4* __restrict__ w1b,
    const float* __restrict__ bnc, const float* __restrict__ move0,
    const float* __restrict__ move1,
    const uint4* __restrict__ bits1, uint4* __restrict__ bits2,
    uint2* __restrict__ res1, float* __restrict__ out)
{
    const int b = blockIdx.x;
    const int js = b & 15;
    const int px = (b >> 4) * 256 + threadIdx.x;
    const int n = px / HW, poff = px % HW;

    const float* xn = x + (size_t)n * 256 * HW;
    const size_t pxi = (size_t)px;
    const uint4* __restrict__ wjs = w1b + js * 72;   // wave-uniform base

    // batched preloads: 8 residual streams (+ 8 idle streams when js<8)
    float rres[8];
    #pragma unroll
    for (int jj = 0; jj < 8; ++jj)
        rres[jj] = xn[(size_t)(js * 8 + jj) * HW + poff];
    float xo[8];
    if (js < 8) {
        #pragma unroll
        for (int jj = 0; jj < 8; ++jj)
            xo[jj] = xn[(size_t)(128 + js * 8 + jj) * HW + poff];
    }

    const int row = poff / WW, col = poff % WW;
    const int rok0 = (row >= 1), rok2 = (row <= HH - 2);
    const int cok0 = (col >= 1), cok2 = (col <= WW - 2);
    const uint32_t rs0 = rok0 ? ~0u : 0u, rs2 = rok2 ? ~0u : 0u;
    const uint32_t csL = cok0 ? ~0u : 0u, csR = cok2 ? ~0u : 0u;
    const int nvbase = ((1 + rok0 + rok2) * (1 + cok0 + cok2)) << 7;

    // window direct from global, row-clamped (masks kill invalid taps)
    const uint4* bsrc = bits1 + (size_t)n * HW;
    const uint4 i00 = bsrc[clampi(poff - 57, 0, HW - 1)];
    const uint4 i01 = bsrc[clampi(poff - 56, 0, HW - 1)];
    const uint4 i02 = bsrc[clampi(poff - 55, 0, HW - 1)];
    const uint4 i10 = bsrc[clampi(poff - 1, 0, HW - 1)];
    const uint4 i11 = bsrc[poff];
    const uint4 i12 = bsrc[clampi(poff + 1, 0, HW - 1)];
    const uint4 i20 = bsrc[clampi(poff + 55, 0, HW - 1)];
    const uint4 i21 = bsrc[clampi(poff + 56, 0, HW - 1)];
    const uint4 i22 = bsrc[clampi(poff + 57, 0, HW - 1)];

    uint32_t bw = 0;
    uint32_t q0 = 0, q1 = 0;        // 8 int8 res1 bytes

    #pragma unroll
    for (int jj = 0; jj < 8; ++jj) {
        const int j = js * 8 + jj;
        int acc = 0;
        acc += PC(wjs[jj * 9 + 0], i00) & (int)(rs0 & csL);
        acc += PC(wjs[jj * 9 + 1], i01) & (int)rs0;
        acc += PC(wjs[jj * 9 + 2], i02) & (int)(rs0 & csR);
        acc += PC(wjs[jj * 9 + 3], i10) & (int)csL;
        acc += PC(wjs[jj * 9 + 4], i11);
        acc += PC(wjs[jj * 9 + 5], i12) & (int)csR;
        acc += PC(wjs[jj * 9 + 6], i20) & (int)(rs2 & csL);
        acc += PC(wjs[jj * 9 + 7], i21) & (int)rs2;
        acc += PC(wjs[jj * 9 + 8], i22) & (int)(rs2 & csR);
        float convf = (float)(nvbase - (acc << 1));
        float bno = __fadd_rn(__fmul_rn(convf, bnc[j]), bnc[128 + j]);
        float v2 = __fadd_rn(bno, rres[jj]);
        float vc = fminf(fmaxf(v2, -1.0f), 1.0f);
        if (js < 8) {
            bw |= (v2 >= 0.0f ? 1u : 0u) << (2 * jj);
            float s = __fadd_rn(xo[jj], move0[js * 8 + jj]);
            bw |= (s >= 0.0f ? 1u : 0u) << (2 * jj + 1);
            uint32_t q = (uint32_t)(uint8_t)(int8_t)__float2int_rn(
                __fmul_rn(vc, 127.0f));
            uint32_t sh = 8 * (jj & 3);
            if (jj < 4) q0 |= q << sh; else q1 |= q << sh;
        } else {
            int m = j - 64;
            __builtin_nontemporal_store(__fadd_rn(vc, move1[2 * m]),
                &out[(size_t)(n * 256 + 4 * m + 1) * HW + poff]);
        }
    }
    if (js < 8) {
        res1[(size_t)js * NPX + pxi] = make_uint2(q0, q1);
        ((uint16_t*)(bits2 + pxi))[js] = (uint16_t)bw;
    }
}

// Kernel C: conv2. out plane 2j; also pass-through planes 4m+3 (m = 4js+mm).
__global__ __launch_bounds__(256) void conv2_kernel(
    const float* __restrict__ x, const uint4* __restrict__ w2b,
    const float* __restrict__ bnc, const float* __restrict__ move0,
    const float* __restrict__ move1,
    const uint4* __restrict__ bits2, const uint2* __restrict__ res1,
    float* __restrict__ out)
{
    const int b = blockIdx.x;
    const int js = b & 15;
    const int px = (b >> 4) * 256 + threadIdx.x;
    const int n = px / HW, poff = px % HW;

    const float* xn = x + (size_t)n * 256 * HW;
    const size_t pxi = (size_t)px;
    const uint4* __restrict__ wjs = w2b + js * 72;   // wave-uniform base

    // batched per-thread global loads (4 int8 even-j residuals + 4 idle floats
    // + 4 pass-through plane inputs)
    const uint32_t rq = ((const uint32_t*)(res1 + (size_t)(js >> 1) * NPX + pxi))[js & 1];
    float ro[4];
    #pragma unroll
    for (int k = 0; k < 4; ++k)
        ro[k] = xn[(size_t)(128 + js * 4 + k) * HW + poff];
    float pt[4];
    #pragma unroll
    for (int k = 0; k < 4; ++k)
        pt[k] = xn[(size_t)(192 + js * 4 + k) * HW + poff];

    const int row = poff / WW, col = poff % WW;
    const int rok0 = (row >= 1), rok2 = (row <= HH - 2);
    const int cok0 = (col >= 1), cok2 = (col <= WW - 2);
    const uint32_t rs0 = rok0 ? ~0u : 0u, rs2 = rok2 ? ~0u : 0u;
    const uint32_t csL = cok0 ? ~0u : 0u, csR = cok2 ? ~0u : 0u;
    const int nvbase = ((1 + rok0 + rok2) * (1 + cok0 + cok2)) << 7;

    const uint4* bsrc = bits2 + (size_t)n * HW;
    const uint4 i00 = bsrc[clampi(poff - 57, 0, HW - 1)];
    const uint4 i01 = bsrc[clampi(poff - 56, 0, HW - 1)];
    const uint4 i02 = bsrc[clampi(poff - 55, 0, HW - 1)];
    const uint4 i10 = bsrc[clampi(poff - 1, 0, HW - 1)];
    const uint4 i11 = bsrc[poff];
    const uint4 i12 = bsrc[clampi(poff + 1, 0, HW - 1)];
    const uint4 i20 = bsrc[clampi(poff + 55, 0, HW - 1)];
    const uint4 i21 = bsrc[clampi(poff + 56, 0, HW - 1)];
    const uint4 i22 = bsrc[clampi(poff + 57, 0, HW - 1)];

    #pragma unroll
    for (int jj = 0; jj < 8; ++jj) {
        const int j = js * 8 + jj;
        int acc = 0;
        acc += PC(wjs[jj * 9 + 0], i00) & (int)(rs0 & csL);
        acc += PC(wjs[jj * 9 + 1], i01) & (int)rs0;
        acc += PC(wjs[jj * 9 + 2], i02) & (int)(rs0 & csR);
        acc += PC(wjs[jj * 9 + 3], i10) & (int)csL;
        acc += PC(wjs[jj * 9 + 4], i11);
        acc += PC(wjs[jj * 9 + 5], i12) & (int)csR;
        acc += PC(wjs[jj * 9 + 6], i20) & (int)(rs2 & csL);
        acc += PC(wjs[jj * 9 + 7], i21) & (int)rs2;
        acc += PC(wjs[jj * 9 + 8], i22) & (int)(rs2 & csR);
        float convf = (float)(nvbase - (acc << 1));
        float bno = __fadd_rn(__fmul_rn(convf, bnc[256 + j]), bnc[384 + j]);
        float resv;
        if (jj & 1) {
            resv = __fadd_rn(ro[jj >> 1], move0[j >> 1]);
        } else {
            int8_t q = (int8_t)(uint8_t)(rq >> (8 * (jj >> 1)));
            resv = __fmul_rn(__int2float_rn((int)q), 1.0f / 127.0f);
        }
        float v2 = __fadd_rn(bno, resv);
        float vc = fminf(fmaxf(v2, -1.0f), 1.0f);
        __builtin_nontemporal_store(vc,
            &out[(size_t)(n * 256 + 2 * j) * HW + poff]);
    }

    // pass-through planes 4m+3, m = 4js+mm
    #pragma unroll
    for (int mm = 0; mm < 4; ++mm) {
        int m = js * 4 + mm;
        float v = __fadd_rn(__fadd_rn(pt[mm], move0[64 + m]), move1[2 * m + 1]);
        __builtin_nontemporal_store(v,
            &out[(size_t)(n * 256 + 4 * m + 3) * HW + poff]);
    }
}

extern "C" void kernel_launch(void* const* d_in, const int* in_sizes, int n_in,
                              void* d_out, int out_size, void* d_ws, size_t ws_size,
                              hipStream_t stream)
{
    const float* x   = (const float*)d_in[0];
    const float* w1  = (const float*)d_in[1];
    const float* w2  = (const float*)d_in[2];
    const float* g1  = (const float*)d_in[3];
    const float* b1  = (const float*)d_in[4];
    const float* m1  = (const float*)d_in[5];
    const float* v1  = (const float*)d_in[6];
    const float* g2  = (const float*)d_in[7];
    const float* b2  = (const float*)d_in[8];
    const float* m2  = (const float*)d_in[9];
    const float* v2  = (const float*)d_in[10];
    const float* mv0 = (const float*)d_in[11];
    const float* mv1 = (const float*)d_in[12];

    uint8_t* ws = (uint8_t*)d_ws;
    uint4* w1b = (uint4*)(ws + WS_W1B);
    uint4* w2b = (uint4*)(ws + WS_W2B);
    float* bnc = (float*)(ws + WS_BN);
    uint4* bits2 = (uint4*)(ws + WS_BITS2);
    uint4* bits1 = (uint4*)(ws + WS_BITS1);
    uint2* res1 = (uint2*)(ws + WS_RES1);
    float* outp = (float*)d_out;

    hipLaunchKernelGGL(binpack_kernel, dim3(784 + 10), dim3(256), 0, stream,
                       x, w1, w2, g1, b1, m1, v1, g2, b2, m2, v2,
                       bits1, w1b, w2b, bnc);
    hipLaunchKernelGGL(conv1_kernel, dim3(392 * 16), dim3(256), 0, stream,
                       x, w1b, bnc, mv0, mv1, bits1, bits2, res1, outp);
    hipLaunchKernelGGL(conv2_kernel, dim3(392 * 16), dim3(256), 0, stream,
                       x, w2b, bnc, mv0, mv1, bits2, res1, outp);
}